// Round 4
// baseline (584.485 us; speedup 1.0000x reference)
//
#include <hip/hip_runtime.h>
#include <hip/hip_bf16.h>
#include <math.h>

// Problem dims (fixed by setup_inputs)
#define BSZ    16
#define DMODEL 1024
#define QLEN   256
#define MLEN   256
#define KLEN   512
#define NHEAD  16
#define DHEAD  64
#define DINNER 4096

typedef __bf16 bf16;
typedef bf16 bf16x8 __attribute__((ext_vector_type(8)));
typedef float f32x4 __attribute__((ext_vector_type(4)));

#define GLOBAL_AS __attribute__((address_space(1)))
#define LDS_AS    __attribute__((address_space(3)))

// ================= prep: all casts + all transposes, one launch =================
// Transpose write phase: packed 4x bf16 (8B) stores (round 4; was 4x 2B scalar).
__global__ __launch_bounds__(256) void prep_k(
    const float* __restrict__ Wqkv, const float* __restrict__ Wr,
    const float* __restrict__ Wo,   const float* __restrict__ W1,
    const float* __restrict__ W2,   const float* __restrict__ uss,
    const float* __restrict__ mems, const float* __restrict__ z1ss,
    const float* __restrict__ pos_emb,
    bf16* __restrict__ WqkvB, bf16* __restrict__ WrB, bf16* __restrict__ WoB,
    bf16* __restrict__ W1B,   bf16* __restrict__ W2B, bf16* __restrict__ ussV,
    bf16* __restrict__ catT,  bf16* __restrict__ posT,
    bf16* __restrict__ ussQ,  bf16* __restrict__ ussK)
{
    if (blockIdx.x < 21504) {
        long long i = (long long)blockIdx.x * 256 + threadIdx.x;
        const float* src; bf16* dst; long long soff, doff;
        if      (i <  786432) { src = Wqkv; dst = WqkvB; soff = doff = i; }
        else if (i < 1048576) { src = Wr;   dst = WrB;   soff = doff = i -  786432; }
        else if (i < 1310720) { src = Wo;   dst = WoB;   soff = doff = i - 1048576; }
        else if (i < 2359296) { src = W1;   dst = W1B;   soff = doff = i - 1310720; }
        else if (i < 3407872) { src = W2;   dst = W2B;   soff = doff = i - 2359296; }
        else {
            long long u = i - 3407872, b = u >> 17, r = u & 131071;
            src = uss; dst = ussV; soff = b * 393216 + 262144 + r; doff = u;
        }
        float4 v = ((const float4*)src)[soff];
        bf16 b0 = (bf16)v.x, b1 = (bf16)v.y, b2 = (bf16)v.z, b3 = (bf16)v.w;
        union { ushort u[4]; uint2 d; } p;
        p.u[0] = *(ushort*)&b0; p.u[1] = *(ushort*)&b1;
        p.u[2] = *(ushort*)&b2; p.u[3] = *(ushort*)&b3;
        ((uint2*)dst)[doff] = p.d;
        return;
    }
    __shared__ float tile[32][33];
    int blk = blockIdx.x - 21504;
    const float* src; bf16* dst; long long soff, dof; int ld, ldo, tr, tc;
    if (blk < 8192) {            // catT: (b,half) src [1024,256] -> dst rows 256
        int bh = blk >> 8, t = blk & 255;
        int b = bh >> 1, half = bh & 1;
        tr = t >> 3; tc = t & 7;
        src = half ? z1ss : mems; soff = (long long)b * 1024 * 256; ld = 256;
        dst = catT; dof = ((long long)b * 512 + half * 256) * 1024; ldo = 1024;
    } else if (blk < 8704) {     // posT: [1024,512] -> [512,1024]
        int u = blk - 8192; tr = u >> 4; tc = u & 15;
        src = pos_emb; soff = 0; ld = 512;
        dst = posT; dof = 0; ldo = 1024;
    } else if (blk < 12800) {    // ussQ: uss[b, n<1024, 256+i] -> [b,i,n]
        int u = blk - 8704; int b = u >> 8, t = u & 255;
        tr = t >> 3; tc = t & 7;
        src = uss; soff = (long long)b * 3072 * 512 + 256; ld = 512;
        dst = ussQ; dof = (long long)b * 256 * 1024; ldo = 1024;
    } else {                     // ussK: uss[b, 1024+n, j] -> [b,j,n]
        int u = blk - 12800; int b = u >> 9, t = u & 511;
        tr = t >> 4; tc = t & 15;
        src = uss; soff = ((long long)b * 3072 + 1024) * 512; ld = 512;
        dst = ussK; dof = (long long)b * 512 * 1024; ldo = 1024;
    }
    int tx = threadIdx.x & 31, ty = threadIdx.x >> 5;
    const float* ip = src + soff;
#pragma unroll
    for (int yy = ty; yy < 32; yy += 8)
        tile[yy][tx] = ip[(long long)(tr * 32 + yy) * ld + tc * 32 + tx];
    __syncthreads();
    // packed transpose write: out-row r = tc*32 + (t>>3), chunk ch = t&7 of 4 els
    int r = threadIdx.x >> 3, ch = threadIdx.x & 7;
    union { ushort u[4]; uint2 d; } pk;
#pragma unroll
    for (int j = 0; j < 4; ++j) {
        bf16 bv = (bf16)tile[ch * 4 + j][r];
        pk.u[j] = *(ushort*)&bv;
    }
    *(uint2*)&dst[dof + (long long)(tc * 32 + r) * ldo + tr * 32 + ch * 4] = pk.d;
}

// ============== merged qkv+rhk MFMA GEMM, flat grid of 1312 blocks ==============
// All tasks: C[128,128] tile of A[M,1024] x B[N,1024]^T, lead dims 1024.
//   id [0,768):    qk  per-batch: A=catT[b], B=WqkvB; live tiles only
//   id [768,800):  rhk: A=posT, B=WrB -> rhkT
//   id [800,1312): v   per-batch: A=WqkvB+2048*1024 (Wv), B=catT[b] -> vB
// BK=64 as two BK=32 half-stages per barrier pair.
// NOTE: identity block mapping. XCD swizzle A/B-tested (round 2): FETCH dropped
// 114->68MB but dur rose 97->124us (L3-fit working set; L2 hotspot). Keep identity.
__global__ __launch_bounds__(256) void qkv_gemm_k(
    const bf16* __restrict__ catT, const bf16* __restrict__ WqkvB,
    const bf16* __restrict__ posT, const bf16* __restrict__ WrB,
    const bf16* __restrict__ ussQ, const bf16* __restrict__ ussK,
    const bf16* __restrict__ ussV,
    bf16* __restrict__ qT, bf16* __restrict__ kT,
    bf16* __restrict__ rhkT, bf16* __restrict__ vB)
{
    __shared__ bf16 lA[2 * 128 * 32];
    __shared__ bf16 lB[2 * 128 * 32];

    int id = blockIdx.x;
    int t = threadIdx.x;
    int w = t >> 6, lane = t & 63;

    const bf16 *Ap, *Bp;
    int mode, bz = 0, m0, n0;
    if (id < 768) {
        bz = id / 48; int r = id % 48;
        if (r < 32) { m0 = 256 + ((r >> 4) << 7); n0 = (r & 15) << 7; }
        else        { int rr = r - 32; m0 = (rr >> 3) << 7; n0 = (8 + (rr & 7)) << 7; }
        Ap = catT + (long long)bz * 512 * 1024; Bp = WqkvB; mode = 0;
    } else if (id < 800) {
        int rr = id - 768; m0 = (rr >> 3) << 7; n0 = (rr & 7) << 7;
        Ap = posT; Bp = WrB; mode = 1;
    } else {
        int rr = id - 800; bz = rr >> 5; int tt = rr & 31;
        m0 = (tt >> 2) << 7; n0 = (tt & 3) << 7;
        Ap = WqkvB + 2048 * 1024; Bp = catT + (long long)bz * 512 * 1024; mode = 2;
    }

    int q = lane >> 4, r16 = lane & 15;
    int wm = w >> 1, wn = w & 1;

    f32x4 acc[4][4];
#pragma unroll
    for (int i = 0; i < 4; ++i)
#pragma unroll
        for (int j = 0; j < 4; ++j)
            acc[i][j] = (f32x4){0.f, 0.f, 0.f, 0.f};

    int srow = lane >> 2;
    int scol = (lane & 3) * 8;

    for (int k0 = 0; k0 < 1024; k0 += 64) {
        __syncthreads();
#pragma unroll
        for (int half = 0; half < 2; ++half) {
#pragma unroll
            for (int issue = 0; issue < 2; ++issue) {
                int c = issue * 4 + w;
                int row = c * 16 + srow;
                int col = k0 + half * 32 + scol;
                __builtin_amdgcn_global_load_lds(
                    (const GLOBAL_AS void*)(Ap + (long long)(m0 + row) * 1024 + col),
                    (LDS_AS void*)(lA + half * 4096 + c * 512 + lane * 8), 16, 0, 0);
                __builtin_amdgcn_global_load_lds(
                    (const GLOBAL_AS void*)(Bp + (long long)(n0 + row) * 1024 + col),
                    (LDS_AS void*)(lB + half * 4096 + c * 512 + lane * 8), 16, 0, 0);
            }
        }
        __syncthreads();
#pragma unroll
        for (int kh = 0; kh < 2; ++kh) {
            bf16x8 af[4], bfr[4];
#pragma unroll
            for (int i = 0; i < 4; ++i)
                af[i] = *(const bf16x8*)&lA[kh * 4096 + (wm * 64 + i * 16 + r16) * 32 + q * 8];
#pragma unroll
            for (int j = 0; j < 4; ++j)
                bfr[j] = *(const bf16x8*)&lB[kh * 4096 + (wn * 64 + j * 16 + r16) * 32 + q * 8];
#pragma unroll
            for (int i = 0; i < 4; ++i)
#pragma unroll
                for (int j = 0; j < 4; ++j)
                    acc[i][j] = __builtin_amdgcn_mfma_f32_16x16x32_bf16(
                        af[i], bfr[j], acc[i][j], 0, 0, 0);
        }
    }

    bool isq = (mode == 0) && (n0 < 1024);
#pragma unroll
    for (int i = 0; i < 4; ++i) {
#pragma unroll
        for (int r = 0; r < 4; ++r) {
            int m = m0 + wm * 64 + i * 16 + q * 4 + r;
#pragma unroll
            for (int j = 0; j < 4; ++j) {
                int n = n0 + wn * 64 + j * 16 + r16;
                float v = acc[i][j][r];
                if (mode == 1) {
                    rhkT[(long long)m * 1024 + n] = (bf16)v;
                } else if (mode == 2) {
                    long long idx = ((long long)bz * 1024 + m) * 512 + n;
                    vB[idx] = (bf16)(v + (float)ussV[idx]);
                } else if (isq) {
                    long long idx = ((long long)(bz * 256 + m - 256) << 10) + n;
                    qT[idx] = (bf16)(v + (float)ussQ[idx]);
                } else {
                    long long idx = ((long long)(bz * 512 + m) << 10) + (n - 1024);
                    kT[idx] = (bf16)(v + (float)ussK[idx]);
                }
            }
        }
    }
}

// ======================================================================
// 256x256 tile, BK=64, 8-wave (512 thr), 8-phase schedule with counted
// vmcnt (T3+T4), st-swizzled LDS (T2), setprio around MFMA (T5).
// Validated on FF1/FF2 at NT=16 (~780 TF effective per full 256-block
// round). NT=4 REGRESSES (round 3, Wo: ~43us vs 25us on 2-phase 128²):
// prologue issues 7/16 staging units and the last 2 iterations drain
// vmcnt(0) -> no steady state. Use only for NT >= 8.
// ======================================================================

__device__ __forceinline__ void stage_a_unit(const bf16* __restrict__ Ag, int ldK,
                                             bf16* sAbuf, int qa, int t) {
    int r  = (t >> 2) & 63;
    int ks = t >> 8;
    int cc = (t & 3) ^ (((t >> 5) & 1) << 1);   // inverse st-swizzle on source
    int col = ks * 32 + cc * 8;
    __builtin_amdgcn_global_load_lds(
        (const GLOBAL_AS void*)(Ag + (long long)(qa * 64 + r) * ldK + col),
        (LDS_AS void*)(sAbuf + qa * 4096 + t * 8), 16, 0, 0);
    __builtin_amdgcn_global_load_lds(
        (const GLOBAL_AS void*)(Ag + (long long)(qa * 64 + 128 + r) * ldK + col),
        (LDS_AS void*)(sAbuf + (qa + 2) * 4096 + t * 8), 16, 0, 0);
}

__device__ __forceinline__ void stage_b_unit(const bf16* __restrict__ Bg, int ldK,
                                             bf16* sBbuf, int qb, int t) {
#pragma unroll
    for (int j = 0; j < 2; ++j) {
        int u  = j * 512 + t;
        int p  = u >> 8;
        int w8 = u & 255;
        int ks = w8 >> 7;
        int r  = (w8 >> 2) & 31;
        int cc = (u & 3) ^ (((t >> 5) & 1) << 1);
        __builtin_amdgcn_global_load_lds(
            (const GLOBAL_AS void*)(Bg + (long long)(p * 64 + qb * 32 + r) * ldK + ks * 32 + cc * 8),
            (LDS_AS void*)(sBbuf + p * 4096 + ks * 2048 + qb * 1024 + r * 32 + (u & 3) * 8),
            16, 0, 0);
    }
}

__device__ __forceinline__ void ld_a(const bf16* sAbuf, int qa, int wm, int lane,
                                     bf16x8 a[4][2]) {
    int r16 = lane & 15, qq = lane >> 4;
    int flip = ((r16 >> 3) & 1) << 4;           // swizzled read (elem bit4)
    const bf16* base = sAbuf + (wm * 2 + qa) * 4096;
#pragma unroll
    for (int mf = 0; mf < 4; ++mf)
#pragma unroll
        for (int ks = 0; ks < 2; ++ks)
            a[mf][ks] = *(const bf16x8*)(base +
                ((ks * 2048 + (mf * 16 + r16) * 32 + qq * 8) ^ flip));
}

__device__ __forceinline__ void ld_b(const bf16* sBbuf, int qb, int wn, int lane,
                                     bf16x8 b[2][2]) {
    int r16 = lane & 15, qq = lane >> 4;
    int flip = ((r16 >> 3) & 1) << 4;
    const bf16* base = sBbuf + wn * 4096 + qb * 1024;
#pragma unroll
    for (int nf = 0; nf < 2; ++nf)
#pragma unroll
        for (int ks = 0; ks < 2; ++ks)
            b[nf][ks] = *(const bf16x8*)(base +
                ((ks * 2048 + (nf * 16 + r16) * 32 + qq * 8) ^ flip));
}

#define PH_SYNC_MFMA(QA, QB)                                                   \
    __builtin_amdgcn_s_barrier();                                              \
    asm volatile("s_waitcnt lgkmcnt(0)" ::: "memory");                         \
    __builtin_amdgcn_s_setprio(1);                                             \
    _Pragma("unroll") for (int ks = 0; ks < 2; ++ks)                           \
    _Pragma("unroll") for (int mf = 0; mf < 4; ++mf)                           \
    _Pragma("unroll") for (int nf = 0; nf < 2; ++nf)                           \
        acc[(QA)*4+mf][(QB)*2+nf] = __builtin_amdgcn_mfma_f32_16x16x32_bf16(   \
            a[mf][ks], b[nf][ks], acc[(QA)*4+mf][(QB)*2+nf], 0, 0, 0);         \
    __builtin_amdgcn_s_setprio(0);                                             \
    __builtin_amdgcn_s_barrier();

// Requires NT >= 2 (use only NT >= 8; see header note). Ap/Bp at (m0,0)/(n0,0).
__device__ __forceinline__ void gemm8_core(
    const bf16* __restrict__ Ap, const bf16* __restrict__ Bp,
    int ldK, int NT, bf16* sA, bf16* sB, f32x4 (&acc)[8][4])
{
    int t = threadIdx.x;
    int lane = t & 63, w = t >> 6;
    int wm = w >> 2, wn = w & 3;

    // prologue: tile0 (4 units -> buf0) + tile1 (B0,A1,B1 -> buf1); A0(1) at ph1(0)
    stage_a_unit(Ap, ldK, sA, 0, t);
    stage_a_unit(Ap, ldK, sA, 1, t);
    stage_b_unit(Bp, ldK, sB, 0, t);
    stage_b_unit(Bp, ldK, sB, 1, t);
    stage_b_unit(Bp + 64, ldK, sB + 16384, 0, t);
    stage_a_unit(Ap + 64, ldK, sA + 16384, 1, t);
    stage_b_unit(Bp + 64, ldK, sB + 16384, 1, t);
    asm volatile("s_waitcnt vmcnt(6)" ::: "memory");   // tile0 fully landed
    __builtin_amdgcn_s_barrier();

    bf16x8 a[4][2], b[2][2];
    for (int g = 0; g < NT; ++g) {
        bf16* AR = sA + (g & 1) * 16384;
        bf16* BR = sB + (g & 1) * 16384;
        bf16* AO = sA + ((g & 1) ^ 1) * 16384;
        const bf16* An = Ap + (long long)(g + 1) * 64;
        const bf16* A2 = Ap + (long long)(g + 2) * 64;
        const bf16* B2 = Bp + (long long)(g + 2) * 64;
        // phase 1: quadrant (0,0)
        ld_a(AR, 0, wm, lane, a);
        ld_b(BR, 0, wn, lane, b);
        if (g + 1 < NT) stage_a_unit(An, ldK, AO, 0, t);
        PH_SYNC_MFMA(0, 0)
        // phase 2: quadrant (1,0)  [B regs reused]
        ld_a(AR, 1, wm, lane, a);
        if (g + 2 < NT) stage_b_unit(B2, ldK, BR, 0, t);
        PH_SYNC_MFMA(1, 0)
        // phase 3: quadrant (1,1)  [A regs reused]
        ld_b(BR, 1, wn, lane, b);
        if (g + 2 < NT) stage_a_unit(A2, ldK, AR, 1, t);
        PH_SYNC_MFMA(1, 1)
        // phase 4: quadrant (0,1)  [A re-read, B reused]
        ld_a(AR, 0, wm, lane, a);
        if (g + 2 < NT) stage_b_unit(B2, ldK, BR, 1, t);
        if (g < NT - 2) asm volatile("s_waitcnt vmcnt(6)" ::: "memory");
        else            asm volatile("s_waitcnt vmcnt(0)" ::: "memory");
        PH_SYNC_MFMA(0, 1)
    }
}

// ------- generic 256x256 8-phase GEMM: C = A[M,K] x B[N,K]^T --------------
// kChunk>0: split-K; split s reads K-chunk s, writes f32 partial to
//   ((s&2)?outF2:outF1) + (s&1)*4194304 floats.  kChunk==0: bf16 out.
__global__ __launch_bounds__(512) void gemm8_k(
    const bf16* __restrict__ A, const bf16* __restrict__ B,
    int N, int K, int kChunk,
    const float* __restrict__ bias, int relu,
    bf16* __restrict__ outB,
    float* __restrict__ outF1, float* __restrict__ outF2)
{
    __shared__ bf16 sm[65536];
    int nwg = gridDim.x, f = blockIdx.x;
    int xcd = f & 7, l = f >> 3;
    int q8 = nwg >> 3, rm = nwg & 7;
    int wg = (xcd < rm) ? (xcd * (q8 + 1) + l)
                        : (rm * (q8 + 1) + (xcd - rm) * q8 + l);
    int ntn = N >> 8;

    int Keff = K, split = 0, tile = wg;
    const bf16* Ap = A;
    const bf16* Bp = B;
    if (kChunk > 0) {
        int nsplit = K / kChunk;
        int tiles = nwg / nsplit;
        split = wg / tiles; tile = wg % tiles;
        Ap += (long long)split * kChunk;
        Bp += (long long)split * kChunk;
        Keff = kChunk;
    }
    int m0 = (tile / ntn) << 8, n0 = (tile % ntn) << 8;

    f32x4 acc[8][4];
#pragma unroll
    for (int i = 0; i < 8; ++i)
#pragma unroll
        for (int j = 0; j < 4; ++j) acc[i][j] = (f32x4){0.f, 0.f, 0.f, 0.f};

    gemm8_core(Ap + (long long)m0 * K, Bp + (long long)n0 * K, K, Keff >> 6,
               sm, sm + 32768, acc);

    int t = threadIdx.x, lane = t & 63, w = t >> 6;
    int wm = w >> 2, wn = w & 3;
    int qq = lane >> 4, r16 = lane & 15;
    if (outB) {
#pragma unroll
        for (int mf = 0; mf < 8; ++mf) {
#pragma unroll
            for (int rr2 = 0; rr2 < 4; ++rr2) {
                int m = m0 + wm * 128 + mf * 16 + qq * 4 + rr2;
#pragma unroll
                for (int nf = 0; nf < 4; ++nf) {
                    int n = n0 + wn * 64 + nf * 16 + r16;
                    float v = acc[mf][nf][rr2];
                    if (bias) v += bias[n];
                    if (relu) v = fmaxf(v, 0.f);
                    outB[(long long)m * N + n] = (bf16)v;
                }
            }
        }
    } else {
        float* oF = ((split & 2) ? outF2 : outF1) + (long long)(split & 1) * 4194304;
#pragma unroll
        for (int mf = 0; mf < 8; ++mf) {
#pragma unroll
            for (int rr2 = 0; rr2 < 4; ++rr2) {
                int m = m0 + wm * 128 + mf * 16 + qq * 4 + rr2;
#pragma unroll
                for (int nf = 0; nf < 4; ++nf) {
                    int n = n0 + wn * 64 + nf * 16 + r16;
                    oF[(long long)m * N + n] = acc[mf][nf][rr2];
                }
            }
        }
    }
}

// ---------------- bf16 MFMA GEMM: 128x128 (Wo split-K; short-K workhorse) ----------------
__global__ __launch_bounds__(256) void gemm_bf16(
    const bf16* __restrict__ A, const bf16* __restrict__ B,
    int M, int N, int K, int kChunk,
    const float* __restrict__ bias, int relu,
    float* __restrict__ outF, long long ofBatch,
    bf16* __restrict__ outB)
{
    __shared__ bf16 lA[2 * 128 * 32];
    __shared__ bf16 lB[2 * 128 * 32];

    int t = threadIdx.x;
    int w = t >> 6, lane = t & 63;
    int m0 = blockIdx.y * 128, n0 = blockIdx.x * 128;
    int bz = blockIdx.z;

    const bf16* Ap = A;
    const bf16* Bp = B;
    float* oF = outF;
    int Keff = K;
    if (kChunk > 0) {
        Ap = A + (long long)bz * kChunk;
        Bp = B + (long long)bz * kChunk;
        if (outF) oF = outF + (long long)bz * ofBatch;
        Keff = kChunk;
    }

    int q = lane >> 4, r16 = lane & 15;
    int wm = w >> 1, wn = w & 1;

    f32x4 acc[4][4];
#pragma unroll
    for (int i = 0; i < 4; ++i)
#pragma unroll
        for (int j = 0; j < 4; ++j)
            acc[i][j] = (f32x4){0.f, 0.f, 0.f, 0.f};

    int srow = lane >> 2;
    int scol = (lane & 3) * 8;

    for (int k0 = 0; k0 < Keff; k0 += 64) {
        __syncthreads();
#pragma unroll
        for (int half = 0; half < 2; ++half) {
#pragma unroll
            for (int issue = 0; issue < 2; ++issue) {
                int c = issue * 4 + w;
                int row = c * 16 + srow;
                int col = k0 + half * 32 + scol;
                __builtin_amdgcn_global_load_lds(
                    (const GLOBAL_AS void*)(Ap + (long long)(m0 + row) * K + col),
                    (LDS_AS void*)(lA + half * 4096 + c * 512 + lane * 8), 16, 0, 0);
                __builtin_amdgcn_global_load_lds(
                    (const GLOBAL_AS void*)(Bp + (long long)(n0 + row) * K + col),
                    (LDS_AS void*)(lB + half * 4096 + c * 512 + lane * 8), 16, 0, 0);
            }
        }
        __syncthreads();
#pragma unroll
        for (int kh = 0; kh < 2; ++kh) {
            bf16x8 af[4], bfr[4];
#pragma unroll
            for (int i = 0; i < 4; ++i)
                af[i] = *(const bf16x8*)&lA[kh * 4096 + (wm * 64 + i * 16 + r16) * 32 + q * 8];
#pragma unroll
            for (int j = 0; j < 4; ++j)
                bfr[j] = *(const bf16x8*)&lB[kh * 4096 + (wn * 64 + j * 16 + r16) * 32 + q * 8];
#pragma unroll
            for (int i = 0; i < 4; ++i)
#pragma unroll
                for (int j = 0; j < 4; ++j)
                    acc[i][j] = __builtin_amdgcn_mfma_f32_16x16x32_bf16(
                        af[i], bfr[j], acc[i][j], 0, 0, 0);
        }
    }

#pragma unroll
    for (int i = 0; i < 4; ++i) {
#pragma unroll
        for (int r = 0; r < 4; ++r) {
            int m = m0 + wm * 64 + i * 16 + q * 4 + r;
#pragma unroll
            for (int j = 0; j < 4; ++j) {
                int n = n0 + wn * 64 + j * 16 + r16;
                float v = acc[i][j][r];
                if (bias) v += bias[n];
                if (relu) v = fmaxf(v, 0.f);
                if (oF)   oF[(long long)m * N + n] = v;
                if (outB) outB[(long long)m * N + n] = (bf16)v;
            }
        }
    }
}

// ---------------- MFMA banded-window rel-pos attention ----------------
__global__ __launch_bounds__(256) void attn_mfma_k(
    const bf16* __restrict__ qT,    // [b,256,1024]
    const bf16* __restrict__ kT,    // [b,512,1024]
    const bf16* __restrict__ vB,    // [b,1024,512]
    const bf16* __restrict__ rhkT,  // [512,1024]
    const float* __restrict__ rwb,  // [16,64]
    const float* __restrict__ rrb,  // [16,64]
    bf16* __restrict__ avT)         // [(b*256+i)*1024 + n*64+d]
{
    __shared__ float sBD[64][132];

    int t = threadIdx.x;
    int w = t >> 6, lane = t & 63;
    int lo = lane & 15, hi = lane >> 4;
    int i0 = blockIdx.x * 64;
    int n  = blockIdx.y;
    int b  = blockIdx.z;

    const bf16* qp = qT + ((long long)(b * 256 + i0 + 16 * w + lo)) * 1024 + n * 64;
    bf16x8 qw[2], qr[2];
#pragma unroll
    for (int ks = 0; ks < 2; ++ks) {
        bf16x8 qv = *(const bf16x8*)(qp + ks * 32 + hi * 8);
        const float* wb = rwb + n * 64 + ks * 32 + hi * 8;
        const float* rb = rrb + n * 64 + ks * 32 + hi * 8;
#pragma unroll
        for (int e = 0; e < 8; ++e) {
            float qf = (float)qv[e];
            qw[ks][e] = (bf16)(qf + wb[e]);
            qr[ks][e] = (bf16)(qf + rb[e]);
        }
    }

    const bf16* rp = rhkT + (long long)384 * 1024 + n * 64;
#pragma unroll
    for (int tj = 0; tj < 8; ++tj) {
        const bf16* bp = rp + (long long)(16 * tj + lo) * 1024;
        f32x4 a = (f32x4){0.f, 0.f, 0.f, 0.f};
        a = __builtin_amdgcn_mfma_f32_16x16x32_bf16(qr[0], *(const bf16x8*)(bp + hi * 8), a, 0, 0, 0);
        a = __builtin_amdgcn_mfma_f32_16x16x32_bf16(qr[1], *(const bf16x8*)(bp + 32 + hi * 8), a, 0, 0, 0);
#pragma unroll
        for (int r = 0; r < 4; ++r)
            sBD[16 * w + hi * 4 + r][16 * tj + lo] = a[r];
    }
    __syncthreads();

    f32x4 ac[12];
    const bf16* kp = kT + ((long long)b * 512 + i0 + 129) * 1024 + n * 64;
#pragma unroll
    for (int tj = 0; tj < 12; ++tj) {
        const bf16* bp = kp + (long long)(16 * tj + lo) * 1024;
        f32x4 a = (f32x4){0.f, 0.f, 0.f, 0.f};
        a = __builtin_amdgcn_mfma_f32_16x16x32_bf16(qw[0], *(const bf16x8*)(bp + hi * 8), a, 0, 0, 0);
        a = __builtin_amdgcn_mfma_f32_16x16x32_bf16(qw[1], *(const bf16x8*)(bp + 32 + hi * 8), a, 0, 0, 0);
        ac[tj] = a;
    }

    float p[12][4], rowmax[4], rowsum[4];
#pragma unroll
    for (int r = 0; r < 4; ++r) rowmax[r] = -1e30f;
#pragma unroll
    for (int tj = 0; tj < 12; ++tj) {
#pragma unroll
        for (int r = 0; r < 4; ++r) {
            int m = 16 * w + hi * 4 + r;
            int jj = 16 * tj + lo;
            int tt = jj - m;
            float v = (tt >= 0 && tt < 128) ? (ac[tj][r] + sBD[m][tt]) * 0.125f
                                            : -1e30f;
            p[tj][r] = v;
            rowmax[r] = fmaxf(rowmax[r], v);
        }
    }
#pragma unroll
    for (int r = 0; r < 4; ++r) {
        float mx = rowmax[r];
#pragma unroll
        for (int msk = 1; msk < 16; msk <<= 1)
            mx = fmaxf(mx, __shfl_xor(mx, msk, 64));
        rowmax[r] = mx;
        rowsum[r] = 0.f;
    }
#pragma unroll
    for (int tj = 0; tj < 12; ++tj) {
#pragma unroll
        for (int r = 0; r < 4; ++r) {
            float e = exp2f((p[tj][r] - rowmax[r]) * 1.44269504f);
            p[tj][r] = e;
            rowsum[r] += e;
        }
    }
#pragma unroll
    for (int r = 0; r < 4; ++r) {
        float s = rowsum[r];
#pragma unroll
        for (int msk = 1; msk < 16; msk <<= 1)
            s += __shfl_xor(s, msk, 64);
        rowsum[r] = 1.f / s;
    }

    bf16* P = (bf16*)&sBD[0][0];
#pragma unroll
    for (int tj = 0; tj < 12; ++tj) {
#pragma unroll
        for (int r = 0; r < 4; ++r) {
            int m = 16 * w + hi * 4 + r;
            P[m * 264 + 16 * tj + lo] = (bf16)(p[tj][r] * rowsum[r]);
        }
    }
    __syncthreads();

    f32x4 oacc[4];
#pragma unroll
    for (int td = 0; td < 4; ++td) oacc[td] = (f32x4){0.f, 0.f, 0.f, 0.f};
    const bf16* vp = vB + ((long long)b * 1024 + n * 64) * 512 + i0 + 129;
#pragma unroll
    for (int ks = 0; ks < 6; ++ks) {
        bf16x8 af = *(const bf16x8*)(P + (16 * w + lo) * 264 + ks * 32 + hi * 8);
#pragma unroll
        for (int td = 0; td < 4; ++td) {
            bf16x8 bv = *(const bf16x8*)(vp + (long long)(16 * td + lo) * 512 + ks * 32 + hi * 8);
            oacc[td] = __builtin_amdgcn_mfma_f32_16x16x32_bf16(af, bv, oacc[td], 0, 0, 0);
        }
    }
    bf16* op = avT + ((long long)(b * 256 + i0 + 16 * w)) * 1024 + n * 64;
#pragma unroll
    for (int td = 0; td < 4; ++td)
#pragma unroll
        for (int r = 0; r < 4; ++r)
            op[(long long)(hi * 4 + r) * 1024 + 16 * td + lo] = (bf16)oacc[td][r];
}

// ------- h = LN(x1a+x1b+bo+z1ssT) -> bf16;  rows of [4096,1024] -------
__global__ __launch_bounds__(256) void ln_bf16_k(
    const float* __restrict__ X1a, const float* __restrict__ X1b,
    const float* __restrict__ bo,  const bf16* __restrict__ catT,
    bf16* __restrict__ H)
{
    int row = blockIdx.x, t = threadIdx.x;
    __shared__ float r1[256], r2[256];
    const float* xa = X1a + (long long)row * 1024;
    const float* xb = X1b + (long long)row * 1024;
    const bf16*  zr = catT + ((long long)(row >> 8) * 512 + 256 + (row & 255)) * 1024;
    float v[4], s = 0.f, ss = 0.f;
#pragma unroll
    for (int u = 0; u < 4; ++u) {
        int c = t + u * 256;
        v[u] = xa[c] + xb[c] + bo[c] + (float)zr[c];
        s += v[u]; ss += v[u] * v[u];
    }
    r1[t] = s; r2[t] = ss;
    __syncthreads();
    for (int off = 128; off > 0; off >>= 1) {
        if (t < off) { r1[t] += r1[t + off]; r2[t] += r2[t + off]; }
        __syncthreads();
    }
    float mean = r1[0] * (1.f / 1024.f);
    float var  = r2[0] * (1.f / 1024.f) - mean * mean;
    float rstd = rsqrtf(var + 1e-5f);
    bf16* hr = H + (long long)row * 1024;
#pragma unroll
    for (int u = 0; u < 4; ++u)
        hr[t + u * 256] = (bf16)((v[u] - mean) * rstd);
}

// ------- out = LN(x2a+x2b+x2c+x2d+b2+h) transposed to [b,d,q] -------
__global__ __launch_bounds__(256) void ln_final_k(
    const bf16* __restrict__ Hb,
    const float* __restrict__ X2a, const float* __restrict__ X2b,
    const float* __restrict__ X2c, const float* __restrict__ X2d,
    const float* __restrict__ b2,
    float* __restrict__ O)
{
    int row = blockIdx.x, t = threadIdx.x;
    int b = row >> 8, qq = row & 255;
    __shared__ float r1[256], r2[256];
    const float* xa = X2a + (long long)row * 1024;
    const float* xb = X2b + (long long)row * 1024;
    const float* xc = X2c + (long long)row * 1024;
    const float* xd = X2d + (long long)row * 1024;
    const bf16*  hr = Hb  + (long long)row * 1024;

    float y[4], s = 0.f, ss = 0.f;
#pragma unroll
    for (int u = 0; u < 4; ++u) {
        int c = t + u * 256;
        y[u] = xa[c] + xb[c] + xc[c] + xd[c] + b2[c] + (float)hr[c];
        s += y[u]; ss += y[u] * y[u];
    }
    r1[t] = s; r2[t] = ss;
    __syncthreads();
    for (int off = 128; off > 0; off >>= 1) {
        if (t < off) { r1[t] += r1[t + off]; r2[t] += r2[t + off]; }
        __syncthreads();
    }
    float mean = r1[0] * (1.f / 1024.f);
    float var  = r2[0] * (1.f / 1024.f) - mean * mean;
    float rstd = rsqrtf(var + 1e-5f);

    float* ob = O + (long long)b * 1024 * 256 + qq;
#pragma unroll
    for (int u = 0; u < 4; ++u)
        ob[(long long)(t + u * 256) * 256] = (y[u] - mean) * rstd;
}

extern "C" void kernel_launch(void* const* d_in, const int* in_sizes, int n_in,
                              void* d_out, int out_size, void* d_ws, size_t ws_size,
                              hipStream_t stream) {
    const float* z1ss    = (const float*)d_in[0];   // [16,1024,256]
    const float* uss     = (const float*)d_in[1];   // [16,3072,512]
    const float* mems    = (const float*)d_in[2];   // [16,1024,256]
    const float* pos_emb = (const float*)d_in[3];   // [1024,512]
    const float* Wqkv    = (const float*)d_in[4];   // [3072,1024]
    const float* Wr      = (const float*)d_in[5];   // [1024,1024]
    const float* Wo      = (const float*)d_in[6];   // [1024,1024]
    const float* bo      = (const float*)d_in[7];   // [1024]
    const float* rwb     = (const float*)d_in[8];   // [16,64]
    const float* rrb     = (const float*)d_in[9];   // [16,64]
    const float* W1      = (const float*)d_in[10];  // [4096,1024]
    const float* b1      = (const float*)d_in[11];  // [4096]
    const float* W2      = (const float*)d_in[12];  // [1024,4096]
    const float* b2      = (const float*)d_in[13];  // [1024]

    char* base = (char*)d_ws;
    // Workspace map (bytes), total 138,412,032 (132 MB). Timeline aliases:
    //   x1a/x1b overlay kTB/vBB (Wo writes after attention reads k/v)
    //   ff_b overlays kTB+vBB   (FF1 writes after ln_bf16 consumed x1a/b)
    //   FF2 split-K=4 f32 partials: x2c @base+0 (catT dead after ln_bf16),
    //     x2d @base+16MB (posT..W1B-head dead after FF1), x2a, x2b (uss* dead).
    bf16*  catT  = (bf16*) (base + 0);               // [16,512,1024]  alive thru ln_bf16
    bf16*  posT  = (bf16*) (base + 16777216);        // [512,1024]
    bf16*  WqkvB = (bf16*) (base + 17825792);        // [3072,1024]
    bf16*  WrB   = (bf16*) (base + 24117248);        // [1024,1024]
    bf16*  WoB   = (bf16*) (base + 26214400);        // [1024,1024]
    bf16*  W1B   = (bf16*) (base + 28311552);        // [4096,1024]
    bf16*  W2B   = (bf16*) (base + 36700160);        // [1024,4096]
    bf16*  qTB   = (bf16*) (base + 45088768);        // [16,256,1024]
    bf16*  kTB   = (bf16*) (base + 53477376);        // [16,512,1024]
    bf16*  vBB   = (bf16*) (base + 70254592);        // [16,1024,512]
    float* x1a   = (float*)(base + 53477376);        // [4096,1024] overlays kTB
    float* x1b   = (float*)(base + 70254592);        // [4096,1024] overlays vBB
    bf16*  ff_b  = (bf16*) (base + 53477376);        // [4096,4096] overlays kTB+vBB
    bf16*  rhkTB = (bf16*) (base + 87031808);        // [512,1024]
    bf16*  avTB  = (bf16*) (base + 88080384);        // [4096,1024]
    bf16*  ussQb = (bf16*) (base + 96468992);        // [16,256,1024]
    bf16*  ussKb = (bf16*) (base + 104857600);       // [16,512,1024]
    bf16*  ussVb = (bf16*) (base + 121634816);       // [16,1024,512]
    float* x2a   = (float*)(base + 96468992);        // FF2 split2 partial
    float* x2b   = (float*)(base + 113246208);       // FF2 split3 partial
    float* x2c   = (float*)(base + 0);               // FF2 split0 partial
    float* x2d   = (float*)(base + 16777216);        // FF2 split1 partial
    bf16*  hB    = (bf16*) (base + 130023424);       // [4096,1024] overlays ussV tail

    // ---- prep: all casts + transposes, one launch ----
    prep_k<<<42496, 256, 0, stream>>>(
        Wqkv, Wr, Wo, W1, W2, uss, mems, z1ss, pos_emb,
        WqkvB, WrB, WoB, W1B, W2B, ussVb, catT, posT, ussQb, ussKb);

    // ---- merged qkv + rhk GEMM (proven 128x128 2-phase, identity mapping) ----
    qkv_gemm_k<<<1312, 256, 0, stream>>>(
        catT, WqkvB, posT, WrB, ussQb, ussKb, ussVb, qTB, kTB, rhkTB, vBB);

    // ---- MFMA banded attention -> avT bf16 [bq, nd] ----
    attn_mfma_k<<<dim3(4, NHEAD, BSZ), 256, 0, stream>>>(
        qTB, kTB, vBB, rhkTB, rwb, rrb, avTB);

    // ---- x1 partials = avT @ Wo^T (split-K=2 on 128² 2-phase; NT too short
    //      for gemm8_core — round-3 A/B: gemm8 split4 was ~43us vs 25us) ----
    gemm_bf16<<<dim3(8, 32, 2), 256, 0, stream>>>(
        avTB, WoB, 4096, 1024, 1024, 512,
        nullptr, 0, x1a, (long long)(x1b - x1a), nullptr);

    // ---- h = LN(x1a+x1b+bo+z1ssT) -> bf16 ----
    ln_bf16_k<<<4096, 256, 0, stream>>>(x1a, x1b, bo, catT, hB);

    // ---- ff = relu(h @ W1^T + b1) -> bf16: 256 blocks of 256x256, 8-phase ----
    gemm8_k<<<256, 512, 0, stream>>>(
        hB, W1B, 4096, 1024, 0, b1, 1, ff_b, nullptr, nullptr);

    // ---- x2 partials = ff @ W2^T (split-K=4, 8-phase, 256 blocks, NT=16) ----
    gemm8_k<<<256, 512, 0, stream>>>(
        ff_b, W2B, 1024, 4096, 1024, nullptr, 0, nullptr,
        x2c /* splits 0,1 */, x2a /* splits 2,3 */);

    // ---- out = LN(x2c+x2d+x2a+x2b+b2+h) transposed to [b,d,q] ----
    ln_final_k<<<4096, 256, 0, stream>>>(
        hB, x2c, x2d, x2a, x2b, b2, (float*)d_out);
}

// Round 5
// 573.770 us; speedup vs baseline: 1.0187x; 1.0187x over previous
//
#include <hip/hip_runtime.h>
#include <hip/hip_bf16.h>
#include <math.h>

// Problem dims (fixed by setup_inputs)
#define BSZ    16
#define DMODEL 1024
#define QLEN   256
#define MLEN   256
#define KLEN   512
#define NHEAD  16
#define DHEAD  64
#define DINNER 4096

typedef __bf16 bf16;
typedef bf16 bf16x8 __attribute__((ext_vector_type(8)));
typedef float f32x4 __attribute__((ext_vector_type(4)));

#define GLOBAL_AS __attribute__((address_space(1)))
#define LDS_AS    __attribute__((address_space(3)))

// ================= prep: all casts + all transposes, one launch =================
// NOTE: transpose writes stay SCALAR. Round-4 A/B: packed uint2 repack via a
// union regressed +33us (suspected SROA failure -> scratch round-trip).
__global__ __launch_bounds__(256) void prep_k(
    const float* __restrict__ Wqkv, const float* __restrict__ Wr,
    const float* __restrict__ Wo,   const float* __restrict__ W1,
    const float* __restrict__ W2,   const float* __restrict__ uss,
    const float* __restrict__ mems, const float* __restrict__ z1ss,
    const float* __restrict__ pos_emb,
    bf16* __restrict__ WqkvB, bf16* __restrict__ WrB, bf16* __restrict__ WoB,
    bf16* __restrict__ W1B,   bf16* __restrict__ W2B, bf16* __restrict__ ussV,
    bf16* __restrict__ catT,  bf16* __restrict__ posT,
    bf16* __restrict__ ussQ,  bf16* __restrict__ ussK)
{
    if (blockIdx.x < 21504) {
        long long i = (long long)blockIdx.x * 256 + threadIdx.x;
        const float* src; bf16* dst; long long soff, doff;
        if      (i <  786432) { src = Wqkv; dst = WqkvB; soff = doff = i; }
        else if (i < 1048576) { src = Wr;   dst = WrB;   soff = doff = i -  786432; }
        else if (i < 1310720) { src = Wo;   dst = WoB;   soff = doff = i - 1048576; }
        else if (i < 2359296) { src = W1;   dst = W1B;   soff = doff = i - 1310720; }
        else if (i < 3407872) { src = W2;   dst = W2B;   soff = doff = i - 2359296; }
        else {
            long long u = i - 3407872, b = u >> 17, r = u & 131071;
            src = uss; dst = ussV; soff = b * 393216 + 262144 + r; doff = u;
        }
        float4 v = ((const float4*)src)[soff];
        bf16 b0 = (bf16)v.x, b1 = (bf16)v.y, b2 = (bf16)v.z, b3 = (bf16)v.w;
        union { ushort u[4]; uint2 d; } p;
        p.u[0] = *(ushort*)&b0; p.u[1] = *(ushort*)&b1;
        p.u[2] = *(ushort*)&b2; p.u[3] = *(ushort*)&b3;
        ((uint2*)dst)[doff] = p.d;
        return;
    }
    __shared__ float tile[32][33];
    int blk = blockIdx.x - 21504;
    const float* src; bf16* dst; long long soff, dof; int ld, ldo, tr, tc;
    if (blk < 8192) {            // catT: (b,half) src [1024,256] -> dst rows 256
        int bh = blk >> 8, t = blk & 255;
        int b = bh >> 1, half = bh & 1;
        tr = t >> 3; tc = t & 7;
        src = half ? z1ss : mems; soff = (long long)b * 1024 * 256; ld = 256;
        dst = catT; dof = ((long long)b * 512 + half * 256) * 1024; ldo = 1024;
    } else if (blk < 8704) {     // posT: [1024,512] -> [512,1024]
        int u = blk - 8192; tr = u >> 4; tc = u & 15;
        src = pos_emb; soff = 0; ld = 512;
        dst = posT; dof = 0; ldo = 1024;
    } else if (blk < 12800) {    // ussQ: uss[b, n<1024, 256+i] -> [b,i,n]
        int u = blk - 8704; int b = u >> 8, t = u & 255;
        tr = t >> 3; tc = t & 7;
        src = uss; soff = (long long)b * 3072 * 512 + 256; ld = 512;
        dst = ussQ; dof = (long long)b * 256 * 1024; ldo = 1024;
    } else {                     // ussK: uss[b, 1024+n, j] -> [b,j,n]
        int u = blk - 12800; int b = u >> 9, t = u & 511;
        tr = t >> 4; tc = t & 15;
        src = uss; soff = ((long long)b * 3072 + 1024) * 512; ld = 512;
        dst = ussK; dof = (long long)b * 512 * 1024; ldo = 1024;
    }
    int tx = threadIdx.x & 31, ty = threadIdx.x >> 5;
    const float* ip = src + soff;
#pragma unroll
    for (int yy = ty; yy < 32; yy += 8)
        tile[yy][tx] = ip[(long long)(tr * 32 + yy) * ld + tc * 32 + tx];
    __syncthreads();
#pragma unroll
    for (int yy = ty; yy < 32; yy += 8)
        dst[dof + (long long)(tc * 32 + yy) * ldo + tr * 32 + tx] = (bf16)tile[tx][yy];
}

// ============== merged qkv+rhk MFMA GEMM, flat grid of 1312 blocks ==============
// All tasks: C[128,128] tile of A[M,1024] x B[N,1024]^T, lead dims 1024.
//   id [0,768):    qk  per-batch: A=catT[b], B=WqkvB; live tiles only
//   id [768,800):  rhk: A=posT, B=WrB -> rhkT
//   id [800,1312): v   per-batch: A=WqkvB+2048*1024 (Wv), B=catT[b] -> vB
// BK=64 as two BK=32 half-stages per barrier pair.
// NOTE: identity block mapping. XCD swizzle A/B-tested (round 2): FETCH dropped
// 114->68MB but dur rose 97->124us (L3-fit working set; L2 hotspot). Keep identity.
__global__ __launch_bounds__(256) void qkv_gemm_k(
    const bf16* __restrict__ catT, const bf16* __restrict__ WqkvB,
    const bf16* __restrict__ posT, const bf16* __restrict__ WrB,
    const bf16* __restrict__ ussQ, const bf16* __restrict__ ussK,
    const bf16* __restrict__ ussV,
    bf16* __restrict__ qT, bf16* __restrict__ kT,
    bf16* __restrict__ rhkT, bf16* __restrict__ vB)
{
    __shared__ bf16 lA[2 * 128 * 32];
    __shared__ bf16 lB[2 * 128 * 32];

    int id = blockIdx.x;
    int t = threadIdx.x;
    int w = t >> 6, lane = t & 63;

    const bf16 *Ap, *Bp;
    int mode, bz = 0, m0, n0;
    if (id < 768) {
        bz = id / 48; int r = id % 48;
        if (r < 32) { m0 = 256 + ((r >> 4) << 7); n0 = (r & 15) << 7; }
        else        { int rr = r - 32; m0 = (rr >> 3) << 7; n0 = (8 + (rr & 7)) << 7; }
        Ap = catT + (long long)bz * 512 * 1024; Bp = WqkvB; mode = 0;
    } else if (id < 800) {
        int rr = id - 768; m0 = (rr >> 3) << 7; n0 = (rr & 7) << 7;
        Ap = posT; Bp = WrB; mode = 1;
    } else {
        int rr = id - 800; bz = rr >> 5; int tt = rr & 31;
        m0 = (tt >> 2) << 7; n0 = (tt & 3) << 7;
        Ap = WqkvB + 2048 * 1024; Bp = catT + (long long)bz * 512 * 1024; mode = 2;
    }

    int q = lane >> 4, r16 = lane & 15;
    int wm = w >> 1, wn = w & 1;

    f32x4 acc[4][4];
#pragma unroll
    for (int i = 0; i < 4; ++i)
#pragma unroll
        for (int j = 0; j < 4; ++j)
            acc[i][j] = (f32x4){0.f, 0.f, 0.f, 0.f};

    int srow = lane >> 2;
    int scol = (lane & 3) * 8;

    for (int k0 = 0; k0 < 1024; k0 += 64) {
        __syncthreads();
#pragma unroll
        for (int half = 0; half < 2; ++half) {
#pragma unroll
            for (int issue = 0; issue < 2; ++issue) {
                int c = issue * 4 + w;
                int row = c * 16 + srow;
                int col = k0 + half * 32 + scol;
                __builtin_amdgcn_global_load_lds(
                    (const GLOBAL_AS void*)(Ap + (long long)(m0 + row) * 1024 + col),
                    (LDS_AS void*)(lA + half * 4096 + c * 512 + lane * 8), 16, 0, 0);
                __builtin_amdgcn_global_load_lds(
                    (const GLOBAL_AS void*)(Bp + (long long)(n0 + row) * 1024 + col),
                    (LDS_AS void*)(lB + half * 4096 + c * 512 + lane * 8), 16, 0, 0);
            }
        }
        __syncthreads();
#pragma unroll
        for (int kh = 0; kh < 2; ++kh) {
            bf16x8 af[4], bfr[4];
#pragma unroll
            for (int i = 0; i < 4; ++i)
                af[i] = *(const bf16x8*)&lA[kh * 4096 + (wm * 64 + i * 16 + r16) * 32 + q * 8];
#pragma unroll
            for (int j = 0; j < 4; ++j)
                bfr[j] = *(const bf16x8*)&lB[kh * 4096 + (wn * 64 + j * 16 + r16) * 32 + q * 8];
#pragma unroll
            for (int i = 0; i < 4; ++i)
#pragma unroll
                for (int j = 0; j < 4; ++j)
                    acc[i][j] = __builtin_amdgcn_mfma_f32_16x16x32_bf16(
                        af[i], bfr[j], acc[i][j], 0, 0, 0);
        }
    }

    bool isq = (mode == 0) && (n0 < 1024);
#pragma unroll
    for (int i = 0; i < 4; ++i) {
#pragma unroll
        for (int r = 0; r < 4; ++r) {
            int m = m0 + wm * 64 + i * 16 + q * 4 + r;
#pragma unroll
            for (int j = 0; j < 4; ++j) {
                int n = n0 + wn * 64 + j * 16 + r16;
                float v = acc[i][j][r];
                if (mode == 1) {
                    rhkT[(long long)m * 1024 + n] = (bf16)v;
                } else if (mode == 2) {
                    long long idx = ((long long)bz * 1024 + m) * 512 + n;
                    vB[idx] = (bf16)(v + (float)ussV[idx]);
                } else if (isq) {
                    long long idx = ((long long)(bz * 256 + m - 256) << 10) + n;
                    qT[idx] = (bf16)(v + (float)ussQ[idx]);
                } else {
                    long long idx = ((long long)(bz * 512 + m) << 10) + (n - 1024);
                    kT[idx] = (bf16)(v + (float)ussK[idx]);
                }
            }
        }
    }
}

// ======================================================================
// 256x256 tile, BK=64, 8-wave (512 thr), 8-phase schedule with counted
// vmcnt (T3+T4), st-swizzled LDS (T2), setprio around MFMA (T5).
// Validated on FF1/FF2 at NT=16 (~780 TF effective per full 256-block
// round). NT=4 REGRESSES (round 3, Wo: ~43us vs 25us on 2-phase 128²):
// prologue issues 7/16 staging units and the last 2 iterations drain
// vmcnt(0) -> no steady state. Use only for NT >= 8.
// ======================================================================

__device__ __forceinline__ void stage_a_unit(const bf16* __restrict__ Ag, int ldK,
                                             bf16* sAbuf, int qa, int t) {
    int r  = (t >> 2) & 63;
    int ks = t >> 8;
    int cc = (t & 3) ^ (((t >> 5) & 1) << 1);   // inverse st-swizzle on source
    int col = ks * 32 + cc * 8;
    __builtin_amdgcn_global_load_lds(
        (const GLOBAL_AS void*)(Ag + (long long)(qa * 64 + r) * ldK + col),
        (LDS_AS void*)(sAbuf + qa * 4096 + t * 8), 16, 0, 0);
    __builtin_amdgcn_global_load_lds(
        (const GLOBAL_AS void*)(Ag + (long long)(qa * 64 + 128 + r) * ldK + col),
        (LDS_AS void*)(sAbuf + (qa + 2) * 4096 + t * 8), 16, 0, 0);
}

__device__ __forceinline__ void stage_b_unit(const bf16* __restrict__ Bg, int ldK,
                                             bf16* sBbuf, int qb, int t) {
#pragma unroll
    for (int j = 0; j < 2; ++j) {
        int u  = j * 512 + t;
        int p  = u >> 8;
        int w8 = u & 255;
        int ks = w8 >> 7;
        int r  = (w8 >> 2) & 31;
        int cc = (u & 3) ^ (((t >> 5) & 1) << 1);
        __builtin_amdgcn_global_load_lds(
            (const GLOBAL_AS void*)(Bg + (long long)(p * 64 + qb * 32 + r) * ldK + ks * 32 + cc * 8),
            (LDS_AS void*)(sBbuf + p * 4096 + ks * 2048 + qb * 1024 + r * 32 + (u & 3) * 8),
            16, 0, 0);
    }
}

__device__ __forceinline__ void ld_a(const bf16* sAbuf, int qa, int wm, int lane,
                                     bf16x8 a[4][2]) {
    int r16 = lane & 15, qq = lane >> 4;
    int flip = ((r16 >> 3) & 1) << 4;           // swizzled read (elem bit4)
    const bf16* base = sAbuf + (wm * 2 + qa) * 4096;
#pragma unroll
    for (int mf = 0; mf < 4; ++mf)
#pragma unroll
        for (int ks = 0; ks < 2; ++ks)
            a[mf][ks] = *(const bf16x8*)(base +
                ((ks * 2048 + (mf * 16 + r16) * 32 + qq * 8) ^ flip));
}

__device__ __forceinline__ void ld_b(const bf16* sBbuf, int qb, int wn, int lane,
                                     bf16x8 b[2][2]) {
    int r16 = lane & 15, qq = lane >> 4;
    int flip = ((r16 >> 3) & 1) << 4;
    const bf16* base = sBbuf + wn * 4096 + qb * 1024;
#pragma unroll
    for (int nf = 0; nf < 2; ++nf)
#pragma unroll
        for (int ks = 0; ks < 2; ++ks)
            b[nf][ks] = *(const bf16x8*)(base +
                ((ks * 2048 + (nf * 16 + r16) * 32 + qq * 8) ^ flip));
}

#define PH_SYNC_MFMA(QA, QB)                                                   \
    __builtin_amdgcn_s_barrier();                                              \
    asm volatile("s_waitcnt lgkmcnt(0)" ::: "memory");                         \
    __builtin_amdgcn_s_setprio(1);                                             \
    _Pragma("unroll") for (int ks = 0; ks < 2; ++ks)                           \
    _Pragma("unroll") for (int mf = 0; mf < 4; ++mf)                           \
    _Pragma("unroll") for (int nf = 0; nf < 2; ++nf)                           \
        acc[(QA)*4+mf][(QB)*2+nf] = __builtin_amdgcn_mfma_f32_16x16x32_bf16(   \
            a[mf][ks], b[nf][ks], acc[(QA)*4+mf][(QB)*2+nf], 0, 0, 0);         \
    __builtin_amdgcn_s_setprio(0);                                             \
    __builtin_amdgcn_s_barrier();

// Requires NT >= 2 (use only NT >= 8; see header note). Ap/Bp at (m0,0)/(n0,0).
__device__ __forceinline__ void gemm8_core(
    const bf16* __restrict__ Ap, const bf16* __restrict__ Bp,
    int ldK, int NT, bf16* sA, bf16* sB, f32x4 (&acc)[8][4])
{
    int t = threadIdx.x;
    int lane = t & 63, w = t >> 6;
    int wm = w >> 2, wn = w & 3;

    // prologue: tile0 (4 units -> buf0) + tile1 (B0,A1,B1 -> buf1); A0(1) at ph1(0)
    stage_a_unit(Ap, ldK, sA, 0, t);
    stage_a_unit(Ap, ldK, sA, 1, t);
    stage_b_unit(Bp, ldK, sB, 0, t);
    stage_b_unit(Bp, ldK, sB, 1, t);
    stage_b_unit(Bp + 64, ldK, sB + 16384, 0, t);
    stage_a_unit(Ap + 64, ldK, sA + 16384, 1, t);
    stage_b_unit(Bp + 64, ldK, sB + 16384, 1, t);
    asm volatile("s_waitcnt vmcnt(6)" ::: "memory");   // tile0 fully landed
    __builtin_amdgcn_s_barrier();

    bf16x8 a[4][2], b[2][2];
    for (int g = 0; g < NT; ++g) {
        bf16* AR = sA + (g & 1) * 16384;
        bf16* BR = sB + (g & 1) * 16384;
        bf16* AO = sA + ((g & 1) ^ 1) * 16384;
        const bf16* An = Ap + (long long)(g + 1) * 64;
        const bf16* A2 = Ap + (long long)(g + 2) * 64;
        const bf16* B2 = Bp + (long long)(g + 2) * 64;
        // phase 1: quadrant (0,0)
        ld_a(AR, 0, wm, lane, a);
        ld_b(BR, 0, wn, lane, b);
        if (g + 1 < NT) stage_a_unit(An, ldK, AO, 0, t);
        PH_SYNC_MFMA(0, 0)
        // phase 2: quadrant (1,0)  [B regs reused]
        ld_a(AR, 1, wm, lane, a);
        if (g + 2 < NT) stage_b_unit(B2, ldK, BR, 0, t);
        PH_SYNC_MFMA(1, 0)
        // phase 3: quadrant (1,1)  [A regs reused]
        ld_b(BR, 1, wn, lane, b);
        if (g + 2 < NT) stage_a_unit(A2, ldK, AR, 1, t);
        PH_SYNC_MFMA(1, 1)
        // phase 4: quadrant (0,1)  [A re-read, B reused]
        ld_a(AR, 0, wm, lane, a);
        if (g + 2 < NT) stage_b_unit(B2, ldK, BR, 1, t);
        if (g < NT - 2) asm volatile("s_waitcnt vmcnt(6)" ::: "memory");
        else            asm volatile("s_waitcnt vmcnt(0)" ::: "memory");
        PH_SYNC_MFMA(0, 1)
    }
}

// ------- generic 256x256 8-phase GEMM: C = A[M,K] x B[N,K]^T --------------
// kChunk>0: split-K; split s reads K-chunk s, writes f32 partial to
//   ((s&2)?outF2:outF1) + (s&1)*4194304 floats.  kChunk==0: bf16 out.
__global__ __launch_bounds__(512) void gemm8_k(
    const bf16* __restrict__ A, const bf16* __restrict__ B,
    int N, int K, int kChunk,
    const float* __restrict__ bias, int relu,
    bf16* __restrict__ outB,
    float* __restrict__ outF1, float* __restrict__ outF2)
{
    __shared__ bf16 sm[65536];
    int nwg = gridDim.x, f = blockIdx.x;
    int xcd = f & 7, l = f >> 3;
    int q8 = nwg >> 3, rm = nwg & 7;
    int wg = (xcd < rm) ? (xcd * (q8 + 1) + l)
                        : (rm * (q8 + 1) + (xcd - rm) * q8 + l);
    int ntn = N >> 8;

    int Keff = K, split = 0, tile = wg;
    const bf16* Ap = A;
    const bf16* Bp = B;
    if (kChunk > 0) {
        int nsplit = K / kChunk;
        int tiles = nwg / nsplit;
        split = wg / tiles; tile = wg % tiles;
        Ap += (long long)split * kChunk;
        Bp += (long long)split * kChunk;
        Keff = kChunk;
    }
    int m0 = (tile / ntn) << 8, n0 = (tile % ntn) << 8;

    f32x4 acc[8][4];
#pragma unroll
    for (int i = 0; i < 8; ++i)
#pragma unroll
        for (int j = 0; j < 4; ++j) acc[i][j] = (f32x4){0.f, 0.f, 0.f, 0.f};

    gemm8_core(Ap + (long long)m0 * K, Bp + (long long)n0 * K, K, Keff >> 6,
               sm, sm + 32768, acc);

    int t = threadIdx.x, lane = t & 63, w = t >> 6;
    int wm = w >> 2, wn = w & 3;
    int qq = lane >> 4, r16 = lane & 15;
    if (outB) {
#pragma unroll
        for (int mf = 0; mf < 8; ++mf) {
#pragma unroll
            for (int rr2 = 0; rr2 < 4; ++rr2) {
                int m = m0 + wm * 128 + mf * 16 + qq * 4 + rr2;
#pragma unroll
                for (int nf = 0; nf < 4; ++nf) {
                    int n = n0 + wn * 64 + nf * 16 + r16;
                    float v = acc[mf][nf][rr2];
                    if (bias) v += bias[n];
                    if (relu) v = fmaxf(v, 0.f);
                    outB[(long long)m * N + n] = (bf16)v;
                }
            }
        }
    } else {
        float* oF = ((split & 2) ? outF2 : outF1) + (long long)(split & 1) * 4194304;
#pragma unroll
        for (int mf = 0; mf < 8; ++mf) {
#pragma unroll
            for (int rr2 = 0; rr2 < 4; ++rr2) {
                int m = m0 + wm * 128 + mf * 16 + qq * 4 + rr2;
#pragma unroll
                for (int nf = 0; nf < 4; ++nf) {
                    int n = n0 + wn * 64 + nf * 16 + r16;
                    oF[(long long)m * N + n] = acc[mf][nf][rr2];
                }
            }
        }
    }
}

// ---------------- bf16 MFMA GEMM: 128x128 (Wo split-K; short-K workhorse) ----------------
__global__ __launch_bounds__(256) void gemm_bf16(
    const bf16* __restrict__ A, const bf16* __restrict__ B,
    int M, int N, int K, int kChunk,
    const float* __restrict__ bias, int relu,
    float* __restrict__ outF, long long ofBatch,
    bf16* __restrict__ outB)
{
    __shared__ bf16 lA[2 * 128 * 32];
    __shared__ bf16 lB[2 * 128 * 32];

    int t = threadIdx.x;
    int w = t >> 6, lane = t & 63;
    int m0 = blockIdx.y * 128, n0 = blockIdx.x * 128;
    int bz = blockIdx.z;

    const bf16* Ap = A;
    const bf16* Bp = B;
    float* oF = outF;
    int Keff = K;
    if (kChunk > 0) {
        Ap = A + (long long)bz * kChunk;
        Bp = B + (long long)bz * kChunk;
        if (outF) oF = outF + (long long)bz * ofBatch;
        Keff = kChunk;
    }

    int q = lane >> 4, r16 = lane & 15;
    int wm = w >> 1, wn = w & 1;

    f32x4 acc[4][4];
#pragma unroll
    for (int i = 0; i < 4; ++i)
#pragma unroll
        for (int j = 0; j < 4; ++j)
            acc[i][j] = (f32x4){0.f, 0.f, 0.f, 0.f};

    int srow = lane >> 2;
    int scol = (lane & 3) * 8;

    for (int k0 = 0; k0 < Keff; k0 += 64) {
        __syncthreads();
#pragma unroll
        for (int half = 0; half < 2; ++half) {
#pragma unroll
            for (int issue = 0; issue < 2; ++issue) {
                int c = issue * 4 + w;
                int row = c * 16 + srow;
                int col = k0 + half * 32 + scol;
                __builtin_amdgcn_global_load_lds(
                    (const GLOBAL_AS void*)(Ap + (long long)(m0 + row) * K + col),
                    (LDS_AS void*)(lA + half * 4096 + c * 512 + lane * 8), 16, 0, 0);
                __builtin_amdgcn_global_load_lds(
                    (const GLOBAL_AS void*)(Bp + (long long)(n0 + row) * K + col),
                    (LDS_AS void*)(lB + half * 4096 + c * 512 + lane * 8), 16, 0, 0);
            }
        }
        __syncthreads();
#pragma unroll
        for (int kh = 0; kh < 2; ++kh) {
            bf16x8 af[4], bfr[4];
#pragma unroll
            for (int i = 0; i < 4; ++i)
                af[i] = *(const bf16x8*)&lA[kh * 4096 + (wm * 64 + i * 16 + r16) * 32 + q * 8];
#pragma unroll
            for (int j = 0; j < 4; ++j)
                bfr[j] = *(const bf16x8*)&lB[kh * 4096 + (wn * 64 + j * 16 + r16) * 32 + q * 8];
#pragma unroll
            for (int i = 0; i < 4; ++i)
#pragma unroll
                for (int j = 0; j < 4; ++j)
                    acc[i][j] = __builtin_amdgcn_mfma_f32_16x16x32_bf16(
                        af[i], bfr[j], acc[i][j], 0, 0, 0);
        }
    }

#pragma unroll
    for (int i = 0; i < 4; ++i) {
#pragma unroll
        for (int r = 0; r < 4; ++r) {
            int m = m0 + wm * 64 + i * 16 + q * 4 + r;
#pragma unroll
            for (int j = 0; j < 4; ++j) {
                int n = n0 + wn * 64 + j * 16 + r16;
                float v = acc[i][j][r];
                if (bias) v += bias[n];
                if (relu) v = fmaxf(v, 0.f);
                if (oF)   oF[(long long)m * N + n] = v;
                if (outB) outB[(long long)m * N + n] = (bf16)v;
            }
        }
    }
}

// ---------------- MFMA banded-window rel-pos attention ----------------
__global__ __launch_bounds__(256) void attn_mfma_k(
    const bf16* __restrict__ qT,    // [b,256,1024]
    const bf16* __restrict__ kT,    // [b,512,1024]
    const bf16* __restrict__ vB,    // [b,1024,512]
    const bf16* __restrict__ rhkT,  // [512,1024]
    const float* __restrict__ rwb,  // [16,64]
    const float* __restrict__ rrb,  // [16,64]
    bf16* __restrict__ avT)         // [(b*256+i)*1024 + n*64+d]
{
    __shared__ float sBD[64][132];

    int t = threadIdx.x;
    int w = t >> 6, lane = t & 63;
    int lo = lane & 15, hi = lane >> 4;
    int i0 = blockIdx.x * 64;
    int n  = blockIdx.y;
    int b  = blockIdx.z;

    const bf16* qp = qT + ((long long)(b * 256 + i0 + 16 * w + lo)) * 1024 + n * 64;
    bf16x8 qw[2], qr[2];
#pragma unroll
    for (int ks = 0; ks < 2; ++ks) {
        bf16x8 qv = *(const bf16x8*)(qp + ks * 32 + hi * 8);
        const float* wb = rwb + n * 64 + ks * 32 + hi * 8;
        const float* rb = rrb + n * 64 + ks * 32 + hi * 8;
#pragma unroll
        for (int e = 0; e < 8; ++e) {
            float qf = (float)qv[e];
            qw[ks][e] = (bf16)(qf + wb[e]);
            qr[ks][e] = (bf16)(qf + rb[e]);
        }
    }

    const bf16* rp = rhkT + (long long)384 * 1024 + n * 64;
#pragma unroll
    for (int tj = 0; tj < 8; ++tj) {
        const bf16* bp = rp + (long long)(16 * tj + lo) * 1024;
        f32x4 a = (f32x4){0.f, 0.f, 0.f, 0.f};
        a = __builtin_amdgcn_mfma_f32_16x16x32_bf16(qr[0], *(const bf16x8*)(bp + hi * 8), a, 0, 0, 0);
        a = __builtin_amdgcn_mfma_f32_16x16x32_bf16(qr[1], *(const bf16x8*)(bp + 32 + hi * 8), a, 0, 0, 0);
#pragma unroll
        for (int r = 0; r < 4; ++r)
            sBD[16 * w + hi * 4 + r][16 * tj + lo] = a[r];
    }
    __syncthreads();

    f32x4 ac[12];
    const bf16* kp = kT + ((long long)b * 512 + i0 + 129) * 1024 + n * 64;
#pragma unroll
    for (int tj = 0; tj < 12; ++tj) {
        const bf16* bp = kp + (long long)(16 * tj + lo) * 1024;
        f32x4 a = (f32x4){0.f, 0.f, 0.f, 0.f};
        a = __builtin_amdgcn_mfma_f32_16x16x32_bf16(qw[0], *(const bf16x8*)(bp + hi * 8), a, 0, 0, 0);
        a = __builtin_amdgcn_mfma_f32_16x16x32_bf16(qw[1], *(const bf16x8*)(bp + 32 + hi * 8), a, 0, 0, 0);
        ac[tj] = a;
    }

    float p[12][4], rowmax[4], rowsum[4];
#pragma unroll
    for (int r = 0; r < 4; ++r) rowmax[r] = -1e30f;
#pragma unroll
    for (int tj = 0; tj < 12; ++tj) {
#pragma unroll
        for (int r = 0; r < 4; ++r) {
            int m = 16 * w + hi * 4 + r;
            int jj = 16 * tj + lo;
            int tt = jj - m;
            float v = (tt >= 0 && tt < 128) ? (ac[tj][r] + sBD[m][tt]) * 0.125f
                                            : -1e30f;
            p[tj][r] = v;
            rowmax[r] = fmaxf(rowmax[r], v);
        }
    }
#pragma unroll
    for (int r = 0; r < 4; ++r) {
        float mx = rowmax[r];
#pragma unroll
        for (int msk = 1; msk < 16; msk <<= 1)
            mx = fmaxf(mx, __shfl_xor(mx, msk, 64));
        rowmax[r] = mx;
        rowsum[r] = 0.f;
    }
#pragma unroll
    for (int tj = 0; tj < 12; ++tj) {
#pragma unroll
        for (int r = 0; r < 4; ++r) {
            float e = exp2f((p[tj][r] - rowmax[r]) * 1.44269504f);
            p[tj][r] = e;
            rowsum[r] += e;
        }
    }
#pragma unroll
    for (int r = 0; r < 4; ++r) {
        float s = rowsum[r];
#pragma unroll
        for (int msk = 1; msk < 16; msk <<= 1)
            s += __shfl_xor(s, msk, 64);
        rowsum[r] = 1.f / s;
    }

    bf16* P = (bf16*)&sBD[0][0];
#pragma unroll
    for (int tj = 0; tj < 12; ++tj) {
#pragma unroll
        for (int r = 0; r < 4; ++r) {
            int m = 16 * w + hi * 4 + r;
            P[m * 264 + 16 * tj + lo] = (bf16)(p[tj][r] * rowsum[r]);
        }
    }
    __syncthreads();

    f32x4 oacc[4];
#pragma unroll
    for (int td = 0; td < 4; ++td) oacc[td] = (f32x4){0.f, 0.f, 0.f, 0.f};
    const bf16* vp = vB + ((long long)b * 1024 + n * 64) * 512 + i0 + 129;
#pragma unroll
    for (int ks = 0; ks < 6; ++ks) {
        bf16x8 af = *(const bf16x8*)(P + (16 * w + lo) * 264 + ks * 32 + hi * 8);
#pragma unroll
        for (int td = 0; td < 4; ++td) {
            bf16x8 bv = *(const bf16x8*)(vp + (long long)(16 * td + lo) * 512 + ks * 32 + hi * 8);
            oacc[td] = __builtin_amdgcn_mfma_f32_16x16x32_bf16(af, bv, oacc[td], 0, 0, 0);
        }
    }
    bf16* op = avT + ((long long)(b * 256 + i0 + 16 * w)) * 1024 + n * 64;
#pragma unroll
    for (int td = 0; td < 4; ++td)
#pragma unroll
        for (int r = 0; r < 4; ++r)
            op[(long long)(hi * 4 + r) * 1024 + 16 * td + lo] = (bf16)oacc[td][r];
}

// ------- h = LN(x1a+x1b+bo+z1ssT) -> bf16;  rows of [4096,1024] -------
__global__ __launch_bounds__(256) void ln_bf16_k(
    const float* __restrict__ X1a, const float* __restrict__ X1b,
    const float* __restrict__ bo,  const bf16* __restrict__ catT,
    bf16* __restrict__ H)
{
    int row = blockIdx.x, t = threadIdx.x;
    __shared__ float r1[256], r2[256];
    const float* xa = X1a + (long long)row * 1024;
    const float* xb = X1b + (long long)row * 1024;
    const bf16*  zr = catT + ((long long)(row >> 8) * 512 + 256 + (row & 255)) * 1024;
    float v[4], s = 0.f, ss = 0.f;
#pragma unroll
    for (int u = 0; u < 4; ++u) {
        int c = t + u * 256;
        v[u] = xa[c] + xb[c] + bo[c] + (float)zr[c];
        s += v[u]; ss += v[u] * v[u];
    }
    r1[t] = s; r2[t] = ss;
    __syncthreads();
    for (int off = 128; off > 0; off >>= 1) {
        if (t < off) { r1[t] += r1[t + off]; r2[t] += r2[t + off]; }
        __syncthreads();
    }
    float mean = r1[0] * (1.f / 1024.f);
    float var  = r2[0] * (1.f / 1024.f) - mean * mean;
    float rstd = rsqrtf(var + 1e-5f);
    bf16* hr = H + (long long)row * 1024;
#pragma unroll
    for (int u = 0; u < 4; ++u)
        hr[t + u * 256] = (bf16)((v[u] - mean) * rstd);
}

// ------- out = LN(x2a+x2b+x2c+x2d+b2+h) transposed to [b,d,q] -------
__global__ __launch_bounds__(256) void ln_final_k(
    const bf16* __restrict__ Hb,
    const float* __restrict__ X2a, const float* __restrict__ X2b,
    const float* __restrict__ X2c, const float* __restrict__ X2d,
    const float* __restrict__ b2,
    float* __restrict__ O)
{
    int row = blockIdx.x, t = threadIdx.x;
    int b = row >> 8, qq = row & 255;
    __shared__ float r1[256], r2[256];
    const float* xa = X2a + (long long)row * 1024;
    const float* xb = X2b + (long long)row * 1024;
    const float* xc = X2c + (long long)row * 1024;
    const float* xd = X2d + (long long)row * 1024;
    const bf16*  hr = Hb  + (long long)row * 1024;

    float y[4], s = 0.f, ss = 0.f;
#pragma unroll
    for (int u = 0; u < 4; ++u) {
        int c = t + u * 256;
        y[u] = xa[c] + xb[c] + xc[c] + xd[c] + b2[c] + (float)hr[c];
        s += y[u]; ss += y[u] * y[u];
    }
    r1[t] = s; r2[t] = ss;
    __syncthreads();
    for (int off = 128; off > 0; off >>= 1) {
        if (t < off) { r1[t] += r1[t + off]; r2[t] += r2[t + off]; }
        __syncthreads();
    }
    float mean = r1[0] * (1.f / 1024.f);
    float var  = r2[0] * (1.f / 1024.f) - mean * mean;
    float rstd = rsqrtf(var + 1e-5f);

    float* ob = O + (long long)b * 1024 * 256 + qq;
#pragma unroll
    for (int u = 0; u < 4; ++u)
        ob[(long long)(t + u * 256) * 256] = (y[u] - mean) * rstd;
}

extern "C" void kernel_launch(void* const* d_in, const int* in_sizes, int n_in,
                              void* d_out, int out_size, void* d_ws, size_t ws_size,
                              hipStream_t stream) {
    const float* z1ss    = (const float*)d_in[0];   // [16,1024,256]
    const float* uss     = (const float*)d_in[1];   // [16,3072,512]
    const float* mems    = (const float*)d_in[2];   // [16,1024,256]
    const float* pos_emb = (const float*)d_in[3];   // [1024,512]
    const float* Wqkv    = (const float*)d_in[4];   // [3072,1024]
    const float* Wr      = (const float*)d_in[5];   // [1024,1024]
    const float* Wo      = (const float*)d_in[6];   // [1024,1024]
    const float* bo      = (const float*)d_in[7];   // [1024]
    const float* rwb     = (const float*)d_in[8];   // [16,64]
    const float* rrb     = (const float*)d_in[9];   // [16,64]
    const float* W1      = (const float*)d_in[10];  // [4096,1024]
    const float* b1      = (const float*)d_in[11];  // [4096]
    const float* W2      = (const float*)d_in[12];  // [1024,4096]
    const float* b2      = (const float*)d_in[13];  // [1024]

    char* base = (char*)d_ws;
    // Workspace map (bytes), total 138,412,032 (132 MB). Timeline aliases:
    //   x1a/x1b overlay kTB/vBB (Wo writes after attention reads k/v)
    //   ff_b overlays kTB+vBB   (FF1 writes after ln_bf16 consumed x1a/b)
    //   FF2 split-K=4 f32 partials: x2c @base+0 (catT dead after ln_bf16),
    //     x2d @base+16MB (posT..W1B-head dead after FF1), x2a, x2b (uss* dead).
    bf16*  catT  = (bf16*) (base + 0);               // [16,512,1024]  alive thru ln_bf16
    bf16*  posT  = (bf16*) (base + 16777216);        // [512,1024]
    bf16*  WqkvB = (bf16*) (base + 17825792);        // [3072,1024]
    bf16*  WrB   = (bf16*) (base + 24117248);        // [1024,1024]
    bf16*  WoB   = (bf16*) (base + 26214400);        // [1024,1024]
    bf16*  W1B   = (bf16*) (base + 28311552);        // [4096,1024]
    bf16*  W2B   = (bf16*) (base + 36700160);        // [1024,4096]
    bf16*  qTB   = (bf16*) (base + 45088768);        // [16,256,1024]
    bf16*  kTB   = (bf16*) (base + 53477376);        // [16,512,1024]
    bf16*  vBB   = (bf16*) (base + 70254592);        // [16,1024,512]
    float* x1a   = (float*)(base + 53477376);        // [4096,1024] overlays kTB
    float* x1b   = (float*)(base + 70254592);        // [4096,1024] overlays vBB
    bf16*  ff_b  = (bf16*) (base + 53477376);        // [4096,4096] overlays kTB+vBB
    bf16*  rhkTB = (bf16*) (base + 87031808);        // [512,1024]
    bf16*  avTB  = (bf16*) (base + 88080384);        // [4096,1024]
    bf16*  ussQb = (bf16*) (base + 96468992);        // [16,256,1024]
    bf16*  ussKb = (bf16*) (base + 104857600);       // [16,512,1024]
    bf16*  ussVb = (bf16*) (base + 121634816);       // [16,1024,512]
    float* x2a   = (float*)(base + 96468992);        // FF2 split2 partial
    float* x2b   = (float*)(base + 113246208);       // FF2 split3 partial
    float* x2c   = (float*)(base + 0);               // FF2 split0 partial
    float* x2d   = (float*)(base + 16777216);        // FF2 split1 partial
    bf16*  hB    = (bf16*) (base + 130023424);       // [4096,1024] overlays ussV tail

    // ---- prep: all casts + transposes, one launch ----
    prep_k<<<42496, 256, 0, stream>>>(
        Wqkv, Wr, Wo, W1, W2, uss, mems, z1ss, pos_emb,
        WqkvB, WrB, WoB, W1B, W2B, ussVb, catT, posT, ussQb, ussKb);

    // ---- merged qkv + rhk GEMM (proven 128x128 2-phase, identity mapping) ----
    qkv_gemm_k<<<1312, 256, 0, stream>>>(
        catT, WqkvB, posT, WrB, ussQb, ussKb, ussVb, qTB, kTB, rhkTB, vBB);

    // ---- MFMA banded attention -> avT bf16 [bq, nd] ----
    attn_mfma_k<<<dim3(4, NHEAD, BSZ), 256, 0, stream>>>(
        qTB, kTB, vBB, rhkTB, rwb, rrb, avTB);

    // ---- x1 partials = avT @ Wo^T (split-K=2 on 128² 2-phase; NT too short
    //      for gemm8_core — round-3 A/B: gemm8 split4 was ~43us vs 25us) ----
    gemm_bf16<<<dim3(8, 32, 2), 256, 0, stream>>>(
        avTB, WoB, 4096, 1024, 1024, 512,
        nullptr, 0, x1a, (long long)(x1b - x1a), nullptr);

    // ---- h = LN(x1a+x1b+bo+z1ssT) -> bf16 ----
    ln_bf16_k<<<4096, 256, 0, stream>>>(x1a, x1b, bo, catT, hB);

    // ---- ff = relu(h @ W1^T + b1) -> bf16: 256 blocks of 256x256, 8-phase ----
    gemm8_k<<<256, 512, 0, stream>>>(
        hB, W1B, 4096, 1024, 0, b1, 1, ff_b, nullptr, nullptr);

    // ---- x2 partials = ff @ W2^T (split-K=4, 8-phase, 256 blocks, NT=16) ----
    gemm8_k<<<256, 512, 0, stream>>>(
        ff_b, W2B, 1024, 4096, 1024, nullptr, 0, nullptr,
        x2c /* splits 0,1 */, x2a /* splits 2,3 */);

    // ---- out = LN(x2c+x2d+x2a+x2b+b2+h) transposed to [b,d,q] ----
    ln_final_k<<<4096, 256, 0, stream>>>(
        hB, x2c, x2d, x2a, x2b, b2, (float*)d_out);
}